// Round 6
// baseline (153.806 us; speedup 1.0000x reference)
//
#include <hip/hip_runtime.h>
#include <hip/hip_bf16.h>
#include <stdint.h>

// (B,SQ,SV,D) = (4,4096,4096,64), fp32 in/out.
// Flash attention via bf16 MFMA, 3-term hi/lo split on both matmuls.
// S' = V.Q^T (swapped) so P lands in the PV B-operand layout in-register;
// V row-storage permuted (phi) so P's k-slots are contiguous (v = 8*lg+i).
// Structure: 512 blocks x 256 thr (4 waves). Wave = (qt: 16-q tile, half:
// 2048-key span). LDS = 2 halves x 2 buffers x blob = 76 KB -> 2 blocks/CU
// (two independent barrier domains per CU). One barrier per step; depth-1
// prefetch; each wave waits only its own loads (issued a full step earlier).
#define BATCH 4
#define SQN   4096
#define SVN   4096
#define DIM   64
#define KT    32               // keys per tile
#define NTILE (SVN / KT)       // 128 tiles per batch
#define NSTEPH 64              // tiles per SV-half (2048/32)

#define RMS 72                 // row-major stride (elems): 144B rows, 2-way-free b128
#define TRS 40                 // transposed stride (elems): 80B rows, 2-way-free b128
#define IMG_RM_H 0
#define IMG_RM_L 4608
#define IMG_TR_H 9216          // RM planes = chunks 0..8
#define IMG_TR_L 14336         // TR planes = chunks 9..18
#define BLOB     19456         // 19 x 1024B chunks
#define LDS_BYTES (4 * BLOB)   // 2 halves x 2 buffers = 77824 B -> 2 blocks/CU

typedef __attribute__((ext_vector_type(8))) short bf16x8;
typedef __attribute__((ext_vector_type(4))) float f32x4;
typedef __attribute__((ext_vector_type(4))) unsigned int u32x4;

#if __has_builtin(__builtin_amdgcn_exp2f)
#define EXP2F __builtin_amdgcn_exp2f
#else
#define EXP2F exp2f
#endif

static __device__ __forceinline__ unsigned short bf16_rne(float x) {
  unsigned u = __float_as_uint(x);
  u += 0x7FFFu + ((u >> 16) & 1u);
  return (unsigned short)(u >> 16);
}
static __device__ __forceinline__ float bf16f(unsigned short h) {
  return __uint_as_float((unsigned)h << 16);
}
static __device__ __forceinline__ unsigned cvt_pk_bf16(float lo, float hi) {
  unsigned r;
  asm("v_cvt_pk_bf16_f32 %0, %1, %2" : "=v"(r) : "v"(lo), "v"(hi));
  return r;
}

// ---------------------------------------------------------------------------
// Prep: V fp32 -> per-tile blobs in ws. RM planes: direct b128 stores
// (permuted rows). TR planes: dword-packed LDS exchange (stride-65 pad =
// conflict-free column reads), assemble rows in-register, 16B stores.
// grid = 512 blocks x 256 thr; block = one 32-key tile.
// ---------------------------------------------------------------------------
__global__ __launch_bounds__(256) void vprep_kernel(const float* __restrict__ V,
                                                    char* __restrict__ ws) {
  __shared__ unsigned ex[32][65];   // [vv][d] = h | l<<16 ; 65-pad: col reads hit all banks
  const int b    = blockIdx.x >> 7;
  const int tile = blockIdx.x & 127;
  const int t    = threadIdx.x;
  const int vv   = t >> 3;          // 0..31 key within tile
  const int d0   = (t & 7) * 8;     // 0..56 feature chunk

  const float* src = V + (((size_t)b * SVN + (size_t)tile * KT + vv) * DIM + d0);
  const float4 a0 = ((const float4*)src)[0];
  const float4 a1 = ((const float4*)src)[1];
  const float x[8] = {a0.x, a0.y, a0.z, a0.w, a1.x, a1.y, a1.z, a1.w};

  unsigned short h[8], l[8];
#pragma unroll
  for (int j = 0; j < 8; ++j) {
    h[j] = bf16_rne(x[j]);
    l[j] = bf16_rne(x[j] - bf16f(h[j]));
  }

  char* blob = ws + (size_t)(b * NTILE + tile) * BLOB;

  // RM planes: storage row p = phi^-1(vv): phi(16vt+4lg+r) = 8lg+4vt+r
  const int p = (((vv >> 2) & 1) << 4) | ((vv >> 3) << 2) | (vv & 3);
  bf16x8 vh, vl;
#pragma unroll
  for (int j = 0; j < 8; ++j) { vh[j] = (short)h[j]; vl[j] = (short)l[j]; }
  *(bf16x8*)(blob + IMG_RM_H + (p * RMS + d0) * 2) = vh;
  *(bf16x8*)(blob + IMG_RM_L + (p * RMS + d0) * 2) = vl;

  // exchange: banks (vv + d0 + j) mod 32 -> 2-way max on writes (free)
#pragma unroll
  for (int j = 0; j < 8; ++j) ex[vv][d0 + j] = (unsigned)h[j] | ((unsigned)l[j] << 16);
  __syncthreads();

  // assemble TR rows: thread t -> plane pl, d-row, half hh (16 cols)
  const int r  = t >> 1;           // 0..127
  const int pl = r >> 6;           // 0: H, 1: L
  const int d  = r & 63;
  const int hh = t & 1;
  unsigned w16[16];
#pragma unroll
  for (int c = 0; c < 16; ++c) w16[c] = ex[hh * 16 + c][d];  // banks (c+d)%32: 2-way
  u32x4 o0, o1;
#pragma unroll
  for (int k = 0; k < 8; ++k) {
    const unsigned w0 = w16[2 * k], w1 = w16[2 * k + 1];
    const unsigned dw = pl ? ((w0 >> 16) | (w1 & 0xFFFF0000u))
                           : ((w0 & 0xFFFFu) | (w1 << 16));
    if (k < 4) o0[k] = dw; else o1[k - 4] = dw;
  }
  char* dst = blob + (pl ? IMG_TR_L : IMG_TR_H) + (d * TRS + hh * 16) * 2;
  ((u32x4*)dst)[0] = o0;
  ((u32x4*)dst)[1] = o1;
}

// ---------------------------------------------------------------------------
// Main: 512 blocks x 256 thr. Block = 32 q-rows of one batch.
// wave w: qt = w&1 (16-q tile), half = w>>1 (2048-key span). 2-way merge.
// ---------------------------------------------------------------------------
__global__ __launch_bounds__(256, 2) void attn_kernel(const float* __restrict__ Qg,
                                                      const char* __restrict__ vprep,
                                                      float* __restrict__ out) {
  extern __shared__ char smem[];
  const int raw = blockIdx.x;
  const int lb = (raw & 7) * 64 + (raw >> 3);  // XCD swizzle (512 % 8 == 0)
  const int batch = lb >> 7;
  const int qbase = (lb & 127) * 32;
  const int tid = threadIdx.x;
  const int lane = tid & 63;
  const int wid = tid >> 6;
  const int qt = wid & 1;
  const int half = wid >> 1;
  const int lr = lane & 15;
  const int lg = lane >> 4;

  // ---- Q fragment (x log2e), hi/lo split; B slot (lg,j) <-> d = ks*32+8lg+j
  bf16x8 Qh[2], Ql[2];
  {
    const size_t qrow = (size_t)batch * SQN + qbase + qt * 16 + lr;
#pragma unroll
    for (int ks = 0; ks < 2; ++ks) {
      const float* qp = Qg + qrow * DIM + ks * 32 + 8 * lg;
      const float4 f0 = ((const float4*)qp)[0];
      const float4 f1 = ((const float4*)qp)[1];
      const float xv[8] = {f0.x, f0.y, f0.z, f0.w, f1.x, f1.y, f1.z, f1.w};
#pragma unroll
      for (int j = 0; j < 8; ++j) {
        const float v = xv[j] * 1.44269504088896f;
        const unsigned short hh = bf16_rne(v);
        Qh[ks][j] = (short)hh;
        Ql[ks][j] = (short)bf16_rne(v - bf16f(hh));
      }
    }
  }

  f32x4 Oacc[4];
#pragma unroll
  for (int db = 0; db < 4; ++db) Oacc[db] = (f32x4){0.f, 0.f, 0.f, 0.f};
  float m_ = -1e30f;
  float l_ = 0.f;

  const size_t tb0 = (size_t)(batch * NTILE) * BLOB;

  // per step each wave stages 10 of the 19 chunks (qt0: 0-9, qt1: 9-18; dup 9)
  auto stage = [&](int t, int b) {
    const size_t g0 = tb0 + (size_t)(half * NSTEPH + t) * BLOB;
    char* l0 = smem + (half * 2 + b) * BLOB;
    const int c0 = qt * 9;
#pragma unroll
    for (int k = 0; k < 10; ++k) {
      const int sub = c0 + k;
      __builtin_amdgcn_global_load_lds(
          (const __attribute__((address_space(1))) unsigned int*)(vprep + g0 + sub * 1024 + lane * 16),
          (__attribute__((address_space(3))) unsigned int*)(l0 + sub * 1024), 16, 0, 0);
    }
  };

  stage(0, 0);
  int buf = 0;

  for (int t = 0; t < NSTEPH; ++t) {
    // own 10 loads for tile t were issued a full step ago -> cheap drain
    asm volatile("s_waitcnt vmcnt(0)" ::: "memory");
    __builtin_amdgcn_s_barrier();     // all waves' tile-t chunks now in LDS
    if (t + 1 < NSTEPH) stage(t + 1, buf ^ 1);

    const char* qbuf = smem + (half * 2 + buf) * BLOB;

    // ---- phase A: S' = V.Q^T (3-term) -----------------------------------
    bf16x8 Vh[2][2], Vl[2][2];
#pragma unroll
    for (int vt = 0; vt < 2; ++vt)
#pragma unroll
      for (int ks = 0; ks < 2; ++ks) {
        const int off = ((vt * 16 + lr) * RMS + ks * 32 + 8 * lg) * 2;
        Vh[vt][ks] = *(const bf16x8*)(qbuf + IMG_RM_H + off);
        Vl[vt][ks] = *(const bf16x8*)(qbuf + IMG_RM_L + off);
      }

    f32x4 sacc[2];
    __builtin_amdgcn_s_setprio(1);
#pragma unroll
    for (int vt = 0; vt < 2; ++vt) {
      f32x4 acc = (f32x4){0.f, 0.f, 0.f, 0.f};
#pragma unroll
      for (int ks = 0; ks < 2; ++ks) {
        acc = __builtin_amdgcn_mfma_f32_16x16x32_bf16(Vh[vt][ks], Qh[ks], acc, 0, 0, 0);
        acc = __builtin_amdgcn_mfma_f32_16x16x32_bf16(Vh[vt][ks], Ql[ks], acc, 0, 0, 0);
        acc = __builtin_amdgcn_mfma_f32_16x16x32_bf16(Vl[vt][ks], Qh[ks], acc, 0, 0, 0);
      }
      sacc[vt] = acc;
    }
    __builtin_amdgcn_s_setprio(0);

    // ---- online softmax (log2 domain); p[i] <-> v = 8lg+i = PV B k-slot --
    bf16x8 Ph, Pl;
    {
      float mt = -1e30f;
#pragma unroll
      for (int vt = 0; vt < 2; ++vt)
#pragma unroll
        for (int r = 0; r < 4; ++r) mt = fmaxf(mt, sacc[vt][r]);
      mt = fmaxf(mt, __shfl_xor(mt, 16, 64));
      mt = fmaxf(mt, __shfl_xor(mt, 32, 64));

      float p[8];
      float rs = 0.f;
      if (__any(mt > m_ + 8.0f)) {
        const float mnew = fmaxf(m_, mt);
        const float alpha = EXP2F(m_ - mnew);
#pragma unroll
        for (int vt = 0; vt < 2; ++vt)
#pragma unroll
          for (int r = 0; r < 4; ++r) {
            const float pv = EXP2F(sacc[vt][r] - mnew);
            p[vt * 4 + r] = pv;
            rs += pv;
          }
        rs += __shfl_xor(rs, 16, 64);
        rs += __shfl_xor(rs, 32, 64);
        l_ = l_ * alpha + rs;
        m_ = mnew;
#pragma unroll
        for (int db = 0; db < 4; ++db) Oacc[db] *= alpha;
      } else {
        // deferred (T13): keep old max; P bounded by 2^8
#pragma unroll
        for (int vt = 0; vt < 2; ++vt)
#pragma unroll
          for (int r = 0; r < 4; ++r) {
            const float pv = EXP2F(sacc[vt][r] - m_);
            p[vt * 4 + r] = pv;
            rs += pv;
          }
        rs += __shfl_xor(rs, 16, 64);
        rs += __shfl_xor(rs, 32, 64);
        l_ += rs;
      }

      u32x4 hu, lu;
#pragma unroll
      for (int j = 0; j < 4; ++j) {
        const unsigned hd = cvt_pk_bf16(p[2 * j], p[2 * j + 1]);
        const float h0 = __uint_as_float(hd << 16);
        const float h1 = __uint_as_float(hd & 0xFFFF0000u);
        hu[j] = hd;
        lu[j] = cvt_pk_bf16(p[2 * j] - h0, p[2 * j + 1] - h1);
      }
      Ph = __builtin_bit_cast(bf16x8, hu);
      Pl = __builtin_bit_cast(bf16x8, lu);
    }

    // ---- phase B: PV — A slot (lg,i) = V[8lg+i][d], contiguous b128 ------
    __builtin_amdgcn_s_setprio(1);
#pragma unroll
    for (int db = 0; db < 4; ++db) {
      const int toff = ((db * 16 + lr) * TRS + 8 * lg) * 2;
      const bf16x8 Ah = *(const bf16x8*)(qbuf + IMG_TR_H + toff);
      const bf16x8 Al = *(const bf16x8*)(qbuf + IMG_TR_L + toff);
      Oacc[db] = __builtin_amdgcn_mfma_f32_16x16x32_bf16(Ah, Ph, Oacc[db], 0, 0, 0);
      Oacc[db] = __builtin_amdgcn_mfma_f32_16x16x32_bf16(Al, Ph, Oacc[db], 0, 0, 0);
      Oacc[db] = __builtin_amdgcn_mfma_f32_16x16x32_bf16(Ah, Pl, Oacc[db], 0, 0, 0);
    }
    __builtin_amdgcn_s_setprio(0);

    buf ^= 1;
  }

  __syncthreads();  // loop fully drained; safe to reuse smem for merge

  // ---- 2-way half merge through LDS ----
  float* mbuf = (float*)smem;                      // [2 half][32 q][68]
  float* mlb  = (float*)(smem + 2 * 32 * 68 * 4);  // [2 half][32 q][2]
  {
    const int ridx = half * 32 + qt * 16 + lr;
    float* dst = mbuf + ridx * 68;
#pragma unroll
    for (int db = 0; db < 4; ++db)
#pragma unroll
      for (int r = 0; r < 4; ++r) dst[db * 16 + 4 * lg + r] = Oacc[db][r];
    if (lg == 0) {
      mlb[ridx * 2 + 0] = m_;
      mlb[ridx * 2 + 1] = l_;
    }
  }
  __syncthreads();

  const int q  = tid >> 3;          // 0..31
  const int d0 = (tid & 7) * 8;
  float M = fmaxf(mlb[q * 2], mlb[(32 + q) * 2]);
  float L = 0.f;
  float o[8] = {0, 0, 0, 0, 0, 0, 0, 0};
#pragma unroll
  for (int hf = 0; hf < 2; ++hf) {
    const int ridx = hf * 32 + q;
    const float a = EXP2F(mlb[ridx * 2] - M);
    L += a * mlb[ridx * 2 + 1];
    const float* srcp = mbuf + ridx * 68 + d0;
#pragma unroll
    for (int j = 0; j < 8; ++j) o[j] += a * srcp[j];
  }
  const float inv = 1.0f / L;
  float* op = out + ((size_t)batch * SQN + qbase + q) * DIM + d0;
  float4 w0 = {o[0] * inv, o[1] * inv, o[2] * inv, o[3] * inv};
  float4 w1 = {o[4] * inv, o[5] * inv, o[6] * inv, o[7] * inv};
  ((float4*)op)[0] = w0;
  ((float4*)op)[1] = w1;
}

// ---------------------------------------------------------------------------
extern "C" void kernel_launch(void* const* d_in, const int* in_sizes, int n_in,
                              void* d_out, int out_size, void* d_ws, size_t ws_size,
                              hipStream_t stream) {
  const float* Qg = (const float*)d_in[0];
  const float* Vg = (const float*)d_in[1];
  float* out = (float*)d_out;
  char* ws = (char*)d_ws;
  const size_t need = (size_t)BATCH * NTILE * BLOB;  // 9.96 MB
  if (ws_size < need) return;

  hipFuncSetAttribute((const void*)attn_kernel,
                      hipFuncAttributeMaxDynamicSharedMemorySize, LDS_BYTES);

  vprep_kernel<<<BATCH * NTILE, 256, 0, stream>>>(Vg, ws);
  attn_kernel<<<512, 256, LDS_BYTES, stream>>>(Qg, ws, out);
}